// Round 22
// baseline (32.059 us; speedup 1.0000x reference)
//
#include <hip/hip_runtime.h>
#include <hip/hip_bf16.h>

// MADPSNet fused, round 22: r19 structure (31.9-32.1us verified best) + L4
// K-SPLIT to remove the LAST B duplication. L4 was (2,8): wr=0/1 waves read
// identical B streams (+128KB/block, +32MB L2 = 12.5% of block B traffic;
// B-path measured hypersensitive r5/r11/r16). New L4: 8 col-groups x 2
// K-halves; every B frag read once; kh=1 partials -> LDS (buf0, free after
// L3, XOR-chunk swizzled) -> +1 barrier -> kh=0 adds + bias + stores.
// Same per-wave MFMA and A-read counts. Carried: expert gather, packed-B,
// (1,16) L1-L3, swapped-operand MFMA + vector epilogue, cross-layer B
// prefetch depth 2 post-epilogue, bias hoist, prep early-exit, XCD pinning.

typedef __attribute__((ext_vector_type(8))) short bf16x8;
typedef __attribute__((ext_vector_type(4))) float f32x4;

__device__ __forceinline__ ushort f2b(float x) {
    __hip_bfloat16 h = __float2bfloat16(x);
    return *reinterpret_cast<ushort*>(&h);
}

// ------------------------------------------------------------------ prep ---
// W[e][K][N] fp32 -> Wp[e][fg][s][lane][j] bf16 (MFMA fragment order):
//   n = fg*16 + (lane&15), k = s*32 + (lane>>4)*8 + j,  s = 0..K/32-1
// Early-exit: skip experts not selected by any agent.
__global__ __launch_bounds__(256)
void prep_weights(const float* __restrict__ Ws1, const float* __restrict__ Ws2,
                  const float* __restrict__ Wd1, const float* __restrict__ Wd2,
                  const int* __restrict__ sel_s, const int* __restrict__ sel_d,
                  ushort* __restrict__ W1p, ushort* __restrict__ W2p,
                  ushort* __restrict__ W3p, ushort* __restrict__ W4p)
{
    const int layer = blockIdx.z;
    const int e  = blockIdx.y;
    const int fg = blockIdx.x;

    const int* sel = (layer <= 1) ? sel_s : sel_d;
    bool used = false;
    #pragma unroll
    for (int a = 0; a < 8; ++a) used |= (sel[a] == e);
    if (!used) return;

    const float* W; ushort* Wp; int K, N;
    if (layer == 0)      { W = Ws1; Wp = W1p; K = 256; N = 512; }
    else if (layer == 1) { W = Ws2; Wp = W2p; K = 512; N = 256; }
    else if (layer == 2) { W = Wd1; Wp = W3p; K = 256; N = 512; }
    else                 { W = Wd2; Wp = W4p; K = 512; N = 128; }
    if (fg >= N / 16) return;
    const int NK = K / 32;
    W += (size_t)e * K * N;

    __shared__ float tile[512][17];
    const int tid = threadIdx.x;
    const int n0 = fg * 16;
    for (int idx = tid; idx < K * 16; idx += 256)
        tile[idx >> 4][idx & 15] = W[(size_t)(idx >> 4) * N + n0 + (idx & 15)];
    __syncthreads();
    ushort* dst = Wp + (((size_t)e * (N / 16) + fg) * NK) * 512;
    for (int w = tid; w < NK * 64; w += 256) {
        const int s    = w >> 6;
        const int lane = w & 63;
        const int c    = lane & 15;
        const int kb   = s * 32 + ((lane >> 4) << 3);
        bf16x8 v;
        #pragma unroll
        for (int j = 0; j < 8; ++j)
            v[j] = (short)f2b(tile[kb + j][c]);
        *reinterpret_cast<bf16x8*>(&dst[(size_t)w * 8]) = v;
    }
}

// --------------------------------------------------------------- B peek ---
// (1,16) layers: load fragment j (stream order j = s*F + f).
template<int K, int N, int MG>
__device__ __forceinline__ bf16x8 peekB(const ushort* __restrict__ Wp,
                                        int wid, int lane, int j)
{
    constexpr int NG = 16 / MG;
    constexpr int F  = N / 16 / NG;
    constexpr int NK = K / 32;
    const int wc = wid % NG;
    const ushort* bBase = Wp + ((size_t)(wc * F) * NK) * 512 + (size_t)lane * 8;
    const int f = j % F, s = j / F;
    return *reinterpret_cast<const bf16x8*>(bBase + ((size_t)f * NK + s) * 512);
}

// L4 k-split: wave (wc = wid&7, kh = wid>>3) owns col-group wc, k-steps
// kh*8 + 0..7. Fragment j of its stream = global k-step kh*8+j.
__device__ __forceinline__ bf16x8 peekB4(const ushort* __restrict__ Wp,
                                         int wid, int lane, int j)
{
    const int wc = wid & 7;
    const int kh = wid >> 3;
    return *reinterpret_cast<const bf16x8*>(
        Wp + ((size_t)wc * 16 + kh * 8 + j) * 512 + (size_t)lane * 8);
}

// ----------------------------------------------------------- fused layer ---
// (1,16)/(2,8) generic layer (used for L1-L3 here). A: LDS [64][K] swizzled;
// B: packed global; pb0/pb1 prefetched pre-barrier; bias hoisted pre-k-loop.
template<int K, int N, int MG, int RELU>
__device__ __forceinline__ void layer_mlp(
    const ushort* __restrict__ Wp, const float* __restrict__ bias,
    const ushort* __restrict__ sIn, ushort* __restrict__ sOut,
    float* __restrict__ gOut, int wid, int lane,
    bf16x8 pb0, bf16x8 pb1)
{
    constexpr int NG = 16 / MG;          // col groups
    constexpr int F  = N / 16 / NG;      // frags per wave
    constexpr int M4 = 4 / MG;           // m-frags per wave
    constexpr int NK = K / 32;           // k-steps
    const int r15 = lane & 15, lh = lane >> 4;
    const int wc = wid % NG, wr = wid / NG;
    const int rowBase = wr * (64 / MG);

    const ushort* bBase = Wp + ((size_t)(wc * F) * NK) * 512 + (size_t)lane * 8;

    float4 bv[F];
    #pragma unroll
    for (int f = 0; f < F; ++f)
        bv[f] = *reinterpret_cast<const float4*>(
            &bias[(wc * F + f) * 16 + lh * 4]);

    f32x4 acc[M4][F];
    #pragma unroll
    for (int m = 0; m < M4; ++m)
        #pragma unroll
        for (int f = 0; f < F; ++f)
            acc[m][f] = (f32x4){0.f, 0.f, 0.f, 0.f};

    #pragma unroll
    for (int s = 0; s < NK; ++s) {
        const int k0 = s * 32;
        bf16x8 a[M4];
        #pragma unroll
        for (int m = 0; m < M4; ++m) {
            const int row  = rowBase + m * 16 + r15;
            const int phys = ((k0 >> 3) + lh) ^ (row & 7);
            a[m] = *reinterpret_cast<const bf16x8*>(
                reinterpret_cast<const char*>(sIn) + row * (K * 2) + (phys << 4));
        }
        bf16x8 b[F];
        #pragma unroll
        for (int f = 0; f < F; ++f) {
            const int j = s * F + f;
            if (j == 0)      b[f] = pb0;
            else if (j == 1) b[f] = pb1;
            else b[f] = *reinterpret_cast<const bf16x8*>(
                     bBase + ((size_t)f * NK + s) * 512);
        }
        #pragma unroll
        for (int m = 0; m < M4; ++m)
            #pragma unroll
            for (int f = 0; f < F; ++f)
                acc[m][f] = __builtin_amdgcn_mfma_f32_16x16x32_bf16(
                    b[f], a[m], acc[m][f], 0, 0, 0);
    }

    #pragma unroll
    for (int f = 0; f < F; ++f) {
        const int cbase = (wc * F + f) * 16 + lh * 4;
        #pragma unroll
        for (int m = 0; m < M4; ++m) {
            const int row = rowBase + m * 16 + r15;
            float v0 = acc[m][f][0] + bv[f].x;
            float v1 = acc[m][f][1] + bv[f].y;
            float v2 = acc[m][f][2] + bv[f].z;
            float v3 = acc[m][f][3] + bv[f].w;
            if (RELU) {
                v0 = fmaxf(v0, 0.f); v1 = fmaxf(v1, 0.f);
                v2 = fmaxf(v2, 0.f); v3 = fmaxf(v3, 0.f);
            }
            if (gOut) {
                *reinterpret_cast<float4*>(&gOut[(size_t)row * N + cbase]) =
                    (float4){v0, v1, v2, v3};
            } else {
                const uint lo = ((uint)f2b(v1) << 16) | (uint)f2b(v0);
                const uint hi = ((uint)f2b(v3) << 16) | (uint)f2b(v2);
                const int byteoff = row * (N * 2) +
                    ((((cbase >> 3) ^ (row & 7))) << 4) + ((cbase & 7) << 1);
                *reinterpret_cast<uint2*>(
                    reinterpret_cast<char*>(sOut) + byteoff) = (uint2){lo, hi};
            }
        }
    }
}

// ------------------------------------------------------- L4, K-split ------
// K=512, N=128, no relu, fp32 global out. 16 waves = 8 col-groups x 2
// k-halves; each B frag read exactly once. kh=1 writes fp32 partials to
// pLds (XOR-chunk swizzled, 32KB); after barrier kh=0 adds + bias + stores.
__device__ __forceinline__ int pidx(int row, int col) {
    // float index into pLds[64][128]; float4-chunk XOR swizzle (2-way banks)
    const int chunk = col >> 2;                     // 0..31
    const int phys  = chunk ^ ((row & 7) << 2);
    return row * 128 + (phys << 2);
}

__device__ __forceinline__ void layer_out_ksplit(
    const ushort* __restrict__ Wp, const float* __restrict__ bias,
    const ushort* __restrict__ sIn, float* __restrict__ pLds,
    float* __restrict__ gOut, int wid, int lane,
    bf16x8 pb0, bf16x8 pb1)
{
    constexpr int K = 512, N = 128;
    constexpr int NKH = 8;               // k-steps per half
    const int r15 = lane & 15, lh = lane >> 4;
    const int wc = wid & 7;              // col group
    const int kh = wid >> 3;             // k half

    const ushort* bBase = Wp + ((size_t)wc * 16 + kh * 8) * 512 + (size_t)lane * 8;

    const float4 bv = *reinterpret_cast<const float4*>(&bias[wc * 16 + lh * 4]);

    f32x4 acc[4];
    #pragma unroll
    for (int m = 0; m < 4; ++m) acc[m] = (f32x4){0.f, 0.f, 0.f, 0.f};

    #pragma unroll
    for (int s2 = 0; s2 < NKH; ++s2) {
        const int k0 = (kh * NKH + s2) * 32;
        bf16x8 a[4];
        #pragma unroll
        for (int m = 0; m < 4; ++m) {
            const int row  = m * 16 + r15;
            const int phys = ((k0 >> 3) + lh) ^ (row & 7);
            a[m] = *reinterpret_cast<const bf16x8*>(
                reinterpret_cast<const char*>(sIn) + row * (K * 2) + (phys << 4));
        }
        bf16x8 b;
        if (s2 == 0)      b = pb0;
        else if (s2 == 1) b = pb1;
        else b = *reinterpret_cast<const bf16x8*>(bBase + (size_t)s2 * 512);
        #pragma unroll
        for (int m = 0; m < 4; ++m)
            acc[m] = __builtin_amdgcn_mfma_f32_16x16x32_bf16(
                b, a[m], acc[m], 0, 0, 0);
    }

    // kh=1 publishes partials
    if (kh == 1) {
        #pragma unroll
        for (int m = 0; m < 4; ++m) {
            const int row = m * 16 + r15;
            const int col = wc * 16 + lh * 4;
            *reinterpret_cast<float4*>(&pLds[pidx(row, col)]) =
                (float4){acc[m][0], acc[m][1], acc[m][2], acc[m][3]};
        }
    }
    __syncthreads();
    // kh=0 combines + bias + stores
    if (kh == 0) {
        #pragma unroll
        for (int m = 0; m < 4; ++m) {
            const int row = m * 16 + r15;
            const int col = wc * 16 + lh * 4;
            const float4 p = *reinterpret_cast<const float4*>(&pLds[pidx(row, col)]);
            const float v0 = acc[m][0] + p.x + bv.x;
            const float v1 = acc[m][1] + p.y + bv.y;
            const float v2 = acc[m][2] + p.z + bv.z;
            const float v3 = acc[m][3] + p.w + bv.w;
            *reinterpret_cast<float4*>(&gOut[(size_t)row * N + col]) =
                (float4){v0, v1, v2, v3};
        }
    }
}

// ----------------------------------------------------------- fused kernel ---
__global__ __launch_bounds__(1024, 4)
void madps_fused(const float* __restrict__ X,
                 const int* __restrict__ sel_s, const int* __restrict__ sel_d,
                 const ushort* __restrict__ W1p, const ushort* __restrict__ W2p,
                 const ushort* __restrict__ W3p, const ushort* __restrict__ W4p,
                 const float* __restrict__ bs1, const float* __restrict__ bs2,
                 const float* __restrict__ bd1, const float* __restrict__ bd2,
                 float* __restrict__ out)
{
    constexpr int S = 256, H1 = 512, H2 = 256, D1 = 512, D2 = 128;

    __shared__ __align__(16) ushort buf0[64 * 256];   // 32 KB: X, sh, L4 partials
    __shared__ __align__(16) ushort buf1[64 * 512];   // 64 KB: h, then d

    const int bid   = blockIdx.x;
    const int agent = bid & 7;          // agent == XCD -> weights L2-resident
    const int rb    = bid >> 3;         // row-block within agent (0..31)
    const int tid   = threadIdx.x;
    const int lane  = tid & 63;
    const int wid   = tid >> 6;         // 0..15

    const long long es = sel_s[agent];
    const long long ed = sel_d[agent];

    const ushort* W1e = W1p + (size_t)es * ((H1 / 16) * (S  / 32) * 512);
    const ushort* W2e = W2p + (size_t)es * ((H2 / 16) * (H1 / 32) * 512);
    const ushort* W3e = W3p + (size_t)ed * ((D1 / 16) * (H2 / 32) * 512);
    const ushort* W4e = W4p + (size_t)ed * ((D2 / 16) * (D1 / 32) * 512);

    const float* Xa = X + ((size_t)agent * 2048 + (size_t)rb * 64) * S;

    // prefetch L1's first two B frags (overlaps X-staging + barrier)
    bf16x8 pb0 = peekB<S, H1, 1>(W1e, wid, lane, 0);
    bf16x8 pb1 = peekB<S, H1, 1>(W1e, wid, lane, 1);

    // ---- stage X [64][256] fp32 -> buf0 bf16 (swizzled) ----
    #pragma unroll
    for (int i = 0; i < 4; ++i) {
        const int flat4 = i * 1024 + tid;       // float4 index, 64/row
        const int row = flat4 >> 6;
        const int c4  = flat4 & 63;
        const float4 v = reinterpret_cast<const float4*>(Xa)[flat4];
        ushort4 o;
        o.x = f2b(v.x); o.y = f2b(v.y); o.z = f2b(v.z); o.w = f2b(v.w);
        const int byteoff = (((c4 >> 1) ^ (row & 7)) << 4) | ((c4 & 1) << 3);
        *reinterpret_cast<ushort4*>(
            reinterpret_cast<char*>(buf0) + row * 512 + byteoff) = o;
    }
    __syncthreads();

    // L1: X(buf0, K=256) @ W1e -> relu -> h(buf1, N=512)
    layer_mlp<S, H1, 1, 1>(W1e, bs1 + es * H1, buf0, buf1, nullptr,
                           wid, lane, pb0, pb1);
    pb0 = peekB<H1, H2, 1>(W2e, wid, lane, 0);       // prefetch L2 B
    pb1 = peekB<H1, H2, 1>(W2e, wid, lane, 1);
    __syncthreads();
    // L2: h(buf1, K=512) @ W2e -> relu -> sh(buf0, N=256)
    layer_mlp<H1, H2, 1, 1>(W2e, bs2 + es * H2, buf1, buf0, nullptr,
                            wid, lane, pb0, pb1);
    pb0 = peekB<H2, D1, 1>(W3e, wid, lane, 0);       // prefetch L3 B
    pb1 = peekB<H2, D1, 1>(W3e, wid, lane, 1);
    __syncthreads();
    // L3: sh(buf0, K=256) @ W3e -> relu -> d(buf1, N=512)
    layer_mlp<H2, D1, 1, 1>(W3e, bd1 + ed * D1, buf0, buf1, nullptr,
                            wid, lane, pb0, pb1);
    pb0 = peekB4(W4e, wid, lane, 0);                 // prefetch L4 B (k-split)
    pb1 = peekB4(W4e, wid, lane, 1);
    __syncthreads();
    // L4: d(buf1, K=512) @ W4e + bias -> out fp32 [64][128], K-split 8x2.
    // buf0 (free after L3) holds the fp32 partials.
    float* outP = out + ((size_t)agent * 2048 + (size_t)rb * 64) * D2;
    layer_out_ksplit(W4e, bd2 + ed * D2, buf1,
                     reinterpret_cast<float*>(buf0), outP, wid, lane, pb0, pb1);
}

// --------------------------------------------------------------- launch ---
extern "C" void kernel_launch(void* const* d_in, const int* in_sizes, int n_in,
                              void* d_out, int out_size, void* d_ws, size_t ws_size,
                              hipStream_t stream)
{
    constexpr int E = 8, S = 256, H1 = 512, H2 = 256, D1 = 512, D2 = 128;

    const float* inputs = (const float*)d_in[0];
    const int*   sel_s  = (const int*)d_in[1];
    const int*   sel_d  = (const int*)d_in[2];
    const float* Ws1 = (const float*)d_in[3];
    const float* bs1 = (const float*)d_in[4];
    const float* Ws2 = (const float*)d_in[5];
    const float* bs2 = (const float*)d_in[6];
    const float* Wd1 = (const float*)d_in[7];
    const float* bd1 = (const float*)d_in[8];
    const float* Wd2 = (const float*)d_in[9];
    const float* bd2 = (const float*)d_in[10];
    float* out = (float*)d_out;

    // workspace: packed bf16 weights
    ushort* W1p = (ushort*)d_ws;
    ushort* W2p = W1p + (size_t)E * S * H1;
    ushort* W3p = W2p + (size_t)E * H1 * H2;
    ushort* W4p = W3p + (size_t)E * H2 * D1;

    prep_weights<<<dim3(32, E, 4), 256, 0, stream>>>(
        Ws1, Ws2, Wd1, Wd2, sel_s, sel_d, W1p, W2p, W3p, W4p);

    madps_fused<<<dim3(256), dim3(1024), 0, stream>>>(
        inputs, sel_s, sel_d, W1p, W2p, W3p, W4p,
        bs1, bs2, bd1, bd2, out);
}